// Round 2
// baseline (312.641 us; speedup 1.0000x reference)
//
#include <hip/hip_runtime.h>
#include <stdint.h>

typedef unsigned short u16;
typedef short bf16x8 __attribute__((ext_vector_type(8)));
typedef float f32x4 __attribute__((ext_vector_type(4)));

#define DIN 1024
#define SEQ 2048
#define NB 4
#define MB (1u << 20)

// ---------- helpers ----------

__device__ __forceinline__ u16 f2bf(float f) {
    union { float f; unsigned int u; } c; c.f = f;
    unsigned int r = c.u + 0x7fffu + ((c.u >> 16) & 1u);
    return (u16)(r >> 16);
}

__device__ __forceinline__ float bf2f(u16 h) {
    union { unsigned int u; float f; } c; c.u = ((unsigned int)h) << 16;
    return c.f;
}

__device__ __forceinline__ void gload_lds16(const void* g, void* l) {
    __builtin_amdgcn_global_load_lds(
        (__attribute__((address_space(1))) void*)(uintptr_t)g,
        (__attribute__((address_space(3))) void*)l,
        16, 0, 0);
}

// ---------- plain GEMM mainloop (single bf16) ----------
// C[128x128] += A[128xK] * B[128xK]^T  (both K-major bf16). 4 waves 2x2,
// each wave a 64x64 tile of 4x4 16x16 frags. BK=64, XOR-swizzled LDS
// (byte ^= (row&7)<<4) via pre-swizzled global source (linear LDS dest).

__device__ __forceinline__ void gemm_tile(
    const char* __restrict__ A, const char* __restrict__ B,
    int lda, int ldb, int ksteps, char* smem, f32x4 acc[4][4])
{
    const int lane = threadIdx.x & 63;
    const int wave = threadIdx.x >> 6;

    #pragma unroll
    for (int m = 0; m < 4; ++m)
        #pragma unroll
        for (int n = 0; n < 4; ++n)
            acc[m][n] = (f32x4){0.f, 0.f, 0.f, 0.f};

    const char* ga[4];
    const char* gb[4];
    int ldsoff[4];
    #pragma unroll
    for (int i = 0; i < 4; ++i) {
        int La = (wave * 4 + i) * 1024 + lane * 16;
        int r  = La >> 7;
        int cb = La & 127;
        int sc = cb ^ ((r & 7) << 4);
        ga[i] = A + (size_t)r * (size_t)(lda * 2) + sc;
        gb[i] = B + (size_t)r * (size_t)(ldb * 2) + sc;
        ldsoff[i] = (wave * 4 + i) * 1024;
    }

    const int wr = (wave >> 1) * 64;
    const int wc = (wave & 1) * 64;

    for (int ks = 0; ks < ksteps; ++ks) {
        #pragma unroll
        for (int i = 0; i < 4; ++i) {
            gload_lds16(ga[i], smem + ldsoff[i]);
            gload_lds16(gb[i], smem + 16384 + ldsoff[i]);
            ga[i] += 128;
            gb[i] += 128;
        }
        __syncthreads();

        #pragma unroll
        for (int kk = 0; kk < 2; ++kk) {
            const int kb = kk * 64 + ((lane >> 4) << 4);
            bf16x8 af[4], bfv[4];
            #pragma unroll
            for (int m = 0; m < 4; ++m) {
                int r = wr + m * 16 + (lane & 15);
                af[m] = *(const bf16x8*)(smem + r * 128 + (kb ^ ((r & 7) << 4)));
            }
            #pragma unroll
            for (int n = 0; n < 4; ++n) {
                int r = wc + n * 16 + (lane & 15);
                bfv[n] = *(const bf16x8*)(smem + 16384 + r * 128 + (kb ^ ((r & 7) << 4)));
            }
            #pragma unroll
            for (int m = 0; m < 4; ++m)
                #pragma unroll
                for (int n = 0; n < 4; ++n)
                    acc[m][n] = __builtin_amdgcn_mfma_f32_16x16x32_bf16(
                        af[m], bfv[n], acc[m][n], 0, 0, 0);
        }
        __syncthreads();
    }
}

// ---------- split-precision GEMM mainloop ----------
// acc += Ahi*Bhi^T + Alo*Bhi^T + Ahi*Blo^T  (Ootomo bf16x3, fp32 accum)
// LDS: Ahi[0,16K) Bhi[16K,32K) Alo[32K,48K) Blo[48K,64K)

__device__ __forceinline__ void gemm_tile_split(
    const char* __restrict__ Ah, const char* __restrict__ Al,
    const char* __restrict__ Bh, const char* __restrict__ Bl,
    int lda, int ldb, int ksteps, char* smem, f32x4 acc[4][4])
{
    const int lane = threadIdx.x & 63;
    const int wave = threadIdx.x >> 6;

    #pragma unroll
    for (int m = 0; m < 4; ++m)
        #pragma unroll
        for (int n = 0; n < 4; ++n)
            acc[m][n] = (f32x4){0.f, 0.f, 0.f, 0.f};

    const ptrdiff_t dA = Al - Ah;
    const ptrdiff_t dB = Bl - Bh;

    const char* ga[4];
    const char* gb[4];
    int ldsoff[4];
    #pragma unroll
    for (int i = 0; i < 4; ++i) {
        int La = (wave * 4 + i) * 1024 + lane * 16;
        int r  = La >> 7;
        int cb = La & 127;
        int sc = cb ^ ((r & 7) << 4);
        ga[i] = Ah + (size_t)r * (size_t)(lda * 2) + sc;
        gb[i] = Bh + (size_t)r * (size_t)(ldb * 2) + sc;
        ldsoff[i] = (wave * 4 + i) * 1024;
    }

    const int wr = (wave >> 1) * 64;
    const int wc = (wave & 1) * 64;

    for (int ks = 0; ks < ksteps; ++ks) {
        #pragma unroll
        for (int i = 0; i < 4; ++i) {
            gload_lds16(ga[i],      smem +         ldsoff[i]);
            gload_lds16(gb[i],      smem + 16384 + ldsoff[i]);
            gload_lds16(ga[i] + dA, smem + 32768 + ldsoff[i]);
            gload_lds16(gb[i] + dB, smem + 49152 + ldsoff[i]);
            ga[i] += 128;
            gb[i] += 128;
        }
        __syncthreads();

        #pragma unroll
        for (int kk = 0; kk < 2; ++kk) {
            const int kb = kk * 64 + ((lane >> 4) << 4);
            bf16x8 ah[4], al[4], bh[4], bl[4];
            #pragma unroll
            for (int m = 0; m < 4; ++m) {
                int r = wr + m * 16 + (lane & 15);
                int o = r * 128 + (kb ^ ((r & 7) << 4));
                ah[m] = *(const bf16x8*)(smem + o);
                al[m] = *(const bf16x8*)(smem + 32768 + o);
            }
            #pragma unroll
            for (int n = 0; n < 4; ++n) {
                int r = wc + n * 16 + (lane & 15);
                int o = r * 128 + (kb ^ ((r & 7) << 4));
                bh[n] = *(const bf16x8*)(smem + 16384 + o);
                bl[n] = *(const bf16x8*)(smem + 49152 + o);
            }
            #pragma unroll
            for (int m = 0; m < 4; ++m)
                #pragma unroll
                for (int n = 0; n < 4; ++n) {
                    acc[m][n] = __builtin_amdgcn_mfma_f32_16x16x32_bf16(
                        ah[m], bh[n], acc[m][n], 0, 0, 0);
                    acc[m][n] = __builtin_amdgcn_mfma_f32_16x16x32_bf16(
                        al[m], bh[n], acc[m][n], 0, 0, 0);
                    acc[m][n] = __builtin_amdgcn_mfma_f32_16x16x32_bf16(
                        ah[m], bl[n], acc[m][n], 0, 0, 0);
                }
        }
        __syncthreads();
    }
}

// ---------- kernels ----------

// x fp32 -> bf16 hi + lo residual
__global__ void k_convx(const float* __restrict__ x, u16* __restrict__ xh,
                        u16* __restrict__ xl, int n8) {
    int idx = blockIdx.x * blockDim.x + threadIdx.x;
    int stride = gridDim.x * blockDim.x;
    for (; idx < n8; idx += stride) {
        f32x4 a = ((const f32x4*)x)[(size_t)idx * 2];
        f32x4 b = ((const f32x4*)x)[(size_t)idx * 2 + 1];
        float v[8] = {a[0], a[1], a[2], a[3], b[0], b[1], b[2], b[3]};
        bf16x8 oh, ol;
        #pragma unroll
        for (int j = 0; j < 8; ++j) {
            u16 h = f2bf(v[j]);
            oh[j] = (short)h;
            ol[j] = (short)f2bf(v[j] - bf2f(h));
        }
        ((bf16x8*)xh)[idx] = oh;
        ((bf16x8*)xl)[idx] = ol;
    }
}

// W [1024(k)][1024(n)] fp32 -> Wt hi/lo [3*1024(n)][1024(k)] bf16
__global__ void k_wt(const float* __restrict__ Wq, const float* __restrict__ Wk,
                     const float* __restrict__ Wv, u16* __restrict__ Wh,
                     u16* __restrict__ Wl) {
    __shared__ float tile[32][33];
    const int mtx = blockIdx.z;
    const float* W = (mtx == 0) ? Wq : (mtx == 1 ? Wk : Wv);
    const int n0 = blockIdx.x * 32, k0 = blockIdx.y * 32;
    const int c = threadIdx.x & 31, r0 = threadIdx.x >> 5;
    #pragma unroll
    for (int rr = r0; rr < 32; rr += 8)
        tile[rr][c] = W[(size_t)(k0 + rr) * DIN + n0 + c];
    __syncthreads();
    const size_t base = (size_t)mtx * DIN * DIN;
    #pragma unroll
    for (int rr = r0; rr < 32; rr += 8) {
        float v = tile[c][rr];
        u16 h = f2bf(v);
        Wh[base + (size_t)(n0 + rr) * DIN + k0 + c] = h;
        Wl[base + (size_t)(n0 + rr) * DIN + k0 + c] = f2bf(v - bf2f(h));
    }
}

__global__ void k_bias(const float* __restrict__ bq, const float* __restrict__ bk,
                       const float* __restrict__ bv, float* __restrict__ bp) {
    int i = blockIdx.x * 256 + threadIdx.x;
    float v = (i < 1024) ? bq[i] : (i < 2048 ? bk[i - 1024] : bv[i - 2048]);
    bp[i] = v;
}

// QKV = x @ W^T + bias (split-precision); Q,K stored as hi/lo pairs, V as hi
__global__ __launch_bounds__(256) void k_gemm_qkv(
    const u16* __restrict__ xh, const u16* __restrict__ xl,
    const u16* __restrict__ wh, const u16* __restrict__ wl,
    const float* __restrict__ bp,
    u16* __restrict__ Qh, u16* __restrict__ Ql,
    u16* __restrict__ Kh, u16* __restrict__ Kl, u16* __restrict__ V)
{
    __shared__ __align__(16) char smem[65536];
    f32x4 acc[4][4];
    const int blkN = blockIdx.x;   // 0..23
    const int blkM = blockIdx.y;   // 0..63
    gemm_tile_split((const char*)(xh + (size_t)blkM * 128 * DIN),
                    (const char*)(xl + (size_t)blkM * 128 * DIN),
                    (const char*)(wh + (size_t)blkN * 128 * DIN),
                    (const char*)(wl + (size_t)blkN * 128 * DIN),
                    DIN, DIN, DIN / 64, smem, acc);

    const int lane = threadIdx.x & 63;
    const int wave = threadIdx.x >> 6;
    const int row0 = blkM * 128 + (wave >> 1) * 64;
    const int col0 = blkN * 128 + (wave & 1) * 64;
    #pragma unroll
    for (int n = 0; n < 4; ++n) {
        int col = col0 + n * 16 + (lane & 15);
        int nb = col >> 10, nc = col & 1023;
        float bias = bp[col];
        u16* dh = (nb == 0) ? Qh : (nb == 1 ? Kh : V);
        u16* dl = (nb == 0) ? Ql : (nb == 1 ? Kl : (u16*)0);
        #pragma unroll
        for (int m = 0; m < 4; ++m) {
            #pragma unroll
            for (int j = 0; j < 4; ++j) {
                int row = row0 + m * 16 + (lane >> 4) * 4 + j;
                float v = acc[m][n][j] + bias;
                u16 h = f2bf(v);
                dh[(size_t)row * 1024 + nc] = h;
                if (nb != 2)
                    dl[(size_t)row * 1024 + nc] = f2bf(v - bf2f(h));
            }
        }
    }
}

// V [b][s][d] -> Vt [b][d][s]  (bf16)
__global__ void k_transpose_v(const u16* __restrict__ V, u16* __restrict__ Vt) {
    __shared__ u16 tile[32][33];
    const int b = blockIdx.z;
    const int s0 = blockIdx.x * 32, d0 = blockIdx.y * 32;
    const int c = threadIdx.x & 31, r0 = threadIdx.x >> 5;
    const u16* Vb = V + (size_t)b * SEQ * 1024;
    u16* Vtb = Vt + (size_t)b * 1024 * SEQ;
    #pragma unroll
    for (int rr = r0; rr < 32; rr += 8)
        tile[rr][c] = Vb[(size_t)(s0 + rr) * 1024 + d0 + c];
    __syncthreads();
    #pragma unroll
    for (int rr = r0; rr < 32; rr += 8)
        Vtb[(size_t)(d0 + rr) * SEQ + s0 + c] = tile[c][rr];
}

__device__ __forceinline__ size_t s_off(int b) {
    // per-batch fp32 score buffers, overlaying regions dead by the time
    // scores are written: V(64MB), xb_hi(96MB), xb_lo(112MB), wt+bp(128MB)
    return (b == 0) ? (size_t)64 * MB : (b == 1) ? (size_t)96 * MB
         : (b == 2) ? (size_t)112 * MB : (size_t)128 * MB;
}

// scores[b] = Q[b] @ K[b]^T  (split-precision, fp32 out, unscaled)
__global__ __launch_bounds__(256) void k_gemm_scores(
    const u16* __restrict__ Qh, const u16* __restrict__ Ql,
    const u16* __restrict__ Kh, const u16* __restrict__ Kl,
    char* __restrict__ ws)
{
    __shared__ __align__(16) char smem[65536];
    f32x4 acc[4][4];
    const int b = blockIdx.z;
    const size_t qo = (size_t)b * SEQ * 1024 + (size_t)blockIdx.y * 128 * 1024;
    const size_t ko = (size_t)b * SEQ * 1024 + (size_t)blockIdx.x * 128 * 1024;
    gemm_tile_split((const char*)(Qh + qo), (const char*)(Ql + qo),
                    (const char*)(Kh + ko), (const char*)(Kl + ko),
                    1024, 1024, 1024 / 64, smem, acc);

    float* Sb = (float*)(ws + s_off(b));
    const int lane = threadIdx.x & 63;
    const int wave = threadIdx.x >> 6;
    const int row0 = blockIdx.y * 128 + (wave >> 1) * 64;
    const int col0 = blockIdx.x * 128 + (wave & 1) * 64;
    #pragma unroll
    for (int m = 0; m < 4; ++m)
        #pragma unroll
        for (int n = 0; n < 4; ++n) {
            int col = col0 + n * 16 + (lane & 15);
            #pragma unroll
            for (int j = 0; j < 4; ++j) {
                int row = row0 + m * 16 + (lane >> 4) * 4 + j;
                Sb[(size_t)row * SEQ + col] = acc[m][n][j];
            }
        }
}

// row softmax: one block per row, 2048 fp32 in -> 2048 bf16 out
__global__ __launch_bounds__(256) void k_softmax(
    const char* __restrict__ ws, u16* __restrict__ P)
{
    const int rowg = blockIdx.x;            // 0..8191
    const int b = rowg >> 11, r = rowg & 2047;
    const float* s = (const float*)(ws + s_off(b)) + (size_t)r * SEQ;
    u16* p = P + (size_t)rowg * SEQ;
    const int t = threadIdx.x;

    f32x4 x0 = ((const f32x4*)s)[t * 2];
    f32x4 x1 = ((const f32x4*)s)[t * 2 + 1];
    float v[8] = {x0[0], x0[1], x0[2], x0[3], x1[0], x1[1], x1[2], x1[3]};

    float mx = v[0];
    #pragma unroll
    for (int j = 1; j < 8; ++j) mx = fmaxf(mx, v[j]);
    #pragma unroll
    for (int o = 32; o; o >>= 1) mx = fmaxf(mx, __shfl_xor(mx, o, 64));
    __shared__ float red[8];
    if ((t & 63) == 0) red[t >> 6] = mx;
    __syncthreads();
    mx = fmaxf(fmaxf(red[0], red[1]), fmaxf(red[2], red[3]));

    float sum = 0.f;
    #pragma unroll
    for (int j = 0; j < 8; ++j) { v[j] = __expf(v[j] - mx); sum += v[j]; }
    #pragma unroll
    for (int o = 32; o; o >>= 1) sum += __shfl_xor(sum, o, 64);
    if ((t & 63) == 0) red[4 + (t >> 6)] = sum;
    __syncthreads();
    sum = (red[4] + red[5]) + (red[6] + red[7]);
    float inv = 1.0f / sum;

    bf16x8 o8;
    #pragma unroll
    for (int j = 0; j < 8; ++j) o8[j] = (short)f2bf(v[j] * inv);
    ((bf16x8*)p)[t] = o8;
}

// out[b] = (P[b] @ Vt[b]^T) / 32   (fp32 out)
__global__ __launch_bounds__(256) void k_gemm_pv(
    const u16* __restrict__ P, const u16* __restrict__ Vt, float* __restrict__ out)
{
    __shared__ __align__(16) char smem[32768];
    f32x4 acc[4][4];
    const int b = blockIdx.z;
    const u16* Pb  = P  + (size_t)b * SEQ * SEQ;
    const u16* Vtb = Vt + (size_t)b * 1024 * SEQ;
    gemm_tile((const char*)(Pb  + (size_t)blockIdx.y * 128 * SEQ),
              (const char*)(Vtb + (size_t)blockIdx.x * 128 * SEQ),
              SEQ, SEQ, SEQ / 64, smem, acc);

    float* ob = out + (size_t)b * SEQ * 1024;
    const int lane = threadIdx.x & 63;
    const int wave = threadIdx.x >> 6;
    const int row0 = blockIdx.y * 128 + (wave >> 1) * 64;
    const int col0 = blockIdx.x * 128 + (wave & 1) * 64;
    #pragma unroll
    for (int m = 0; m < 4; ++m)
        #pragma unroll
        for (int n = 0; n < 4; ++n) {
            int col = col0 + n * 16 + (lane & 15);
            #pragma unroll
            for (int j = 0; j < 4; ++j) {
                int row = row0 + m * 16 + (lane >> 4) * 4 + j;
                ob[(size_t)row * 1024 + col] = acc[m][n][j] * 0.03125f;
            }
        }
}

// ---------- launch ----------

extern "C" void kernel_launch(void* const* d_in, const int* in_sizes, int n_in,
                              void* d_out, int out_size, void* d_ws, size_t ws_size,
                              hipStream_t stream) {
    const float* x  = (const float*)d_in[0];
    const float* Wq = (const float*)d_in[1];
    const float* bq = (const float*)d_in[2];
    const float* Wk = (const float*)d_in[3];
    const float* bk = (const float*)d_in[4];
    const float* Wv = (const float*)d_in[5];
    const float* bv = (const float*)d_in[6];
    float* out = (float*)d_out;
    char* ws = (char*)d_ws;

    // workspace layout (MB offsets):
    //  [0,16)   Q_hi            (P overlays after scores are consumed)
    //  [16,32)  Q_lo
    //  [32,48)  K_hi
    //  [48,64)  K_lo
    //  [64,80)  V               (S_0 overlays: V dead after transpose)
    //  [80,96)  Vt
    //  [96,112) xb_hi           (S_1 overlays: dead after QKV gemm)
    //  [112,128) xb_lo          (S_2 overlays)
    //  [128,140) wt_hi+wt_lo    (S_3 overlays [128,144): dead after QKV)
    //  [140,+12KB) bp           (inside S_3 span; dead after QKV)
    u16*  Qh  = (u16*)(ws);
    u16*  Ql  = (u16*)(ws + (size_t)16 * MB);
    u16*  Kh  = (u16*)(ws + (size_t)32 * MB);
    u16*  Kl  = (u16*)(ws + (size_t)48 * MB);
    u16*  V   = (u16*)(ws + (size_t)64 * MB);
    u16*  Vt  = (u16*)(ws + (size_t)80 * MB);
    u16*  xh  = (u16*)(ws + (size_t)96 * MB);
    u16*  xl  = (u16*)(ws + (size_t)112 * MB);
    u16*  wh  = (u16*)(ws + (size_t)128 * MB);
    u16*  wl  = (u16*)(ws + (size_t)134 * MB);
    float* bp = (float*)(ws + (size_t)140 * MB);
    u16*  P   = Qh;  // 16MB bf16, overlays dead Q_hi

    const size_t needed = (size_t)144 * MB;
    if (ws_size < needed) return;

    k_convx<<<2048, 256, 0, stream>>>(x, xh, xl, (NB * SEQ * DIN) / 8);
    k_wt<<<dim3(32, 32, 3), 256, 0, stream>>>(Wq, Wk, Wv, wh, wl);
    k_bias<<<12, 256, 0, stream>>>(bq, bk, bv, bp);
    k_gemm_qkv<<<dim3(24, 64), 256, 0, stream>>>(xh, xl, wh, wl, bp, Qh, Ql, Kh, Kl, V);
    k_transpose_v<<<dim3(SEQ / 32, 1024 / 32, NB), 256, 0, stream>>>(V, Vt);
    k_gemm_scores<<<dim3(SEQ / 128, SEQ / 128, NB), 256, 0, stream>>>(Qh, Ql, Kh, Kl, ws);
    k_softmax<<<NB * SEQ, 256, 0, stream>>>(ws, P);
    k_gemm_pv<<<dim3(1024 / 128, SEQ / 128, NB), 256, 0, stream>>>(P, Vt, out);
}

// Round 3
// 191.784 us; speedup vs baseline: 1.6302x; 1.6302x over previous
//
#include <hip/hip_runtime.h>
#include <stdint.h>

typedef unsigned short u16;
typedef _Float16 f16;
typedef _Float16 f16x8 __attribute__((ext_vector_type(8)));
typedef float f32x4 __attribute__((ext_vector_type(4)));

#define DIN 1024
#define SEQ 2048
#define NB 4
#define MB (1u << 20)

// ---------- helpers ----------

__device__ __forceinline__ void gload_lds16(const void* g, void* l) {
    __builtin_amdgcn_global_load_lds(
        (__attribute__((address_space(1))) void*)(uintptr_t)g,
        (__attribute__((address_space(3))) void*)l,
        16, 0, 0);
}

// ---------- GEMM mainloop (f16 single precision) ----------
// C[128x128] += A[128xK] * B[128xK]^T  (both K-major f16). 4 waves 2x2,
// each wave a 64x64 tile of 4x4 16x16 frags. BK=64, XOR-swizzled LDS
// (byte ^= (row&7)<<4) via pre-swizzled global source (linear LDS dest).

__device__ __forceinline__ void gemm_tile(
    const char* __restrict__ A, const char* __restrict__ B,
    int lda, int ldb, int ksteps, char* smem, f32x4 acc[4][4])
{
    const int lane = threadIdx.x & 63;
    const int wave = threadIdx.x >> 6;

    #pragma unroll
    for (int m = 0; m < 4; ++m)
        #pragma unroll
        for (int n = 0; n < 4; ++n)
            acc[m][n] = (f32x4){0.f, 0.f, 0.f, 0.f};

    const char* ga[4];
    const char* gb[4];
    int ldsoff[4];
    #pragma unroll
    for (int i = 0; i < 4; ++i) {
        int La = (wave * 4 + i) * 1024 + lane * 16;
        int r  = La >> 7;
        int cb = La & 127;
        int sc = cb ^ ((r & 7) << 4);
        ga[i] = A + (size_t)r * (size_t)(lda * 2) + sc;
        gb[i] = B + (size_t)r * (size_t)(ldb * 2) + sc;
        ldsoff[i] = (wave * 4 + i) * 1024;
    }

    const int wr = (wave >> 1) * 64;
    const int wc = (wave & 1) * 64;

    for (int ks = 0; ks < ksteps; ++ks) {
        #pragma unroll
        for (int i = 0; i < 4; ++i) {
            gload_lds16(ga[i], smem + ldsoff[i]);
            gload_lds16(gb[i], smem + 16384 + ldsoff[i]);
            ga[i] += 128;
            gb[i] += 128;
        }
        __syncthreads();

        #pragma unroll
        for (int kk = 0; kk < 2; ++kk) {
            const int kb = kk * 64 + ((lane >> 4) << 4);
            f16x8 af[4], bfv[4];
            #pragma unroll
            for (int m = 0; m < 4; ++m) {
                int r = wr + m * 16 + (lane & 15);
                af[m] = *(const f16x8*)(smem + r * 128 + (kb ^ ((r & 7) << 4)));
            }
            #pragma unroll
            for (int n = 0; n < 4; ++n) {
                int r = wc + n * 16 + (lane & 15);
                bfv[n] = *(const f16x8*)(smem + 16384 + r * 128 + (kb ^ ((r & 7) << 4)));
            }
            #pragma unroll
            for (int m = 0; m < 4; ++m)
                #pragma unroll
                for (int n = 0; n < 4; ++n)
                    acc[m][n] = __builtin_amdgcn_mfma_f32_16x16x32_f16(
                        af[m], bfv[n], acc[m][n], 0, 0, 0);
        }
        __syncthreads();
    }
}

// ---------- kernels ----------

// x fp32 -> f16, 8 elems/thread
__global__ void k_convx(const float* __restrict__ x, f16* __restrict__ xh, int n8) {
    int idx = blockIdx.x * blockDim.x + threadIdx.x;
    int stride = gridDim.x * blockDim.x;
    for (; idx < n8; idx += stride) {
        f32x4 a = ((const f32x4*)x)[(size_t)idx * 2];
        f32x4 b = ((const f32x4*)x)[(size_t)idx * 2 + 1];
        f16x8 o;
        o[0] = (f16)a[0]; o[1] = (f16)a[1]; o[2] = (f16)a[2]; o[3] = (f16)a[3];
        o[4] = (f16)b[0]; o[5] = (f16)b[1]; o[6] = (f16)b[2]; o[7] = (f16)b[3];
        ((f16x8*)xh)[idx] = o;
    }
}

// W [1024(k)][1024(n)] fp32 -> Wt [3*1024(n)][1024(k)] f16 (transpose+convert)
__global__ void k_wt(const float* __restrict__ Wq, const float* __restrict__ Wk,
                     const float* __restrict__ Wv, f16* __restrict__ Wt) {
    __shared__ float tile[32][33];
    const int mtx = blockIdx.z;
    const float* W = (mtx == 0) ? Wq : (mtx == 1 ? Wk : Wv);
    const int n0 = blockIdx.x * 32, k0 = blockIdx.y * 32;
    const int c = threadIdx.x & 31, r0 = threadIdx.x >> 5;
    #pragma unroll
    for (int rr = r0; rr < 32; rr += 8)
        tile[rr][c] = W[(size_t)(k0 + rr) * DIN + n0 + c];
    __syncthreads();
    f16* o = Wt + (size_t)mtx * DIN * DIN;
    #pragma unroll
    for (int rr = r0; rr < 32; rr += 8)
        o[(size_t)(n0 + rr) * DIN + k0 + c] = (f16)tile[c][rr];
}

// QKV = x @ W^T + bias; N packed as [Q|K|V]; f16 outputs
__global__ __launch_bounds__(256) void k_gemm_qkv(
    const f16* __restrict__ xh, const f16* __restrict__ wt,
    const float* __restrict__ bq, const float* __restrict__ bk,
    const float* __restrict__ bv,
    f16* __restrict__ Q, f16* __restrict__ K, f16* __restrict__ V)
{
    __shared__ __align__(16) char smem[32768];
    f32x4 acc[4][4];
    const int blkN = blockIdx.x;   // 0..23
    const int blkM = blockIdx.y;   // 0..63
    gemm_tile((const char*)(xh + (size_t)blkM * 128 * DIN),
              (const char*)(wt + (size_t)blkN * 128 * DIN),
              DIN, DIN, DIN / 64, smem, acc);

    const int lane = threadIdx.x & 63;
    const int wave = threadIdx.x >> 6;
    const int row0 = blkM * 128 + (wave >> 1) * 64;
    const int col0 = blkN * 128 + (wave & 1) * 64;
    #pragma unroll
    for (int n = 0; n < 4; ++n) {
        int col = col0 + n * 16 + (lane & 15);
        int nb = col >> 10, nc = col & 1023;
        const float* bsrc = (nb == 0) ? bq : (nb == 1 ? bk : bv);
        float bias = bsrc[nc];
        f16* dst = (nb == 0) ? Q : (nb == 1 ? K : V);
        #pragma unroll
        for (int m = 0; m < 4; ++m) {
            #pragma unroll
            for (int j = 0; j < 4; ++j) {
                int row = row0 + m * 16 + (lane >> 4) * 4 + j;
                dst[(size_t)row * 1024 + nc] = (f16)(acc[m][n][j] + bias);
            }
        }
    }
}

// V [b][s][d] -> Vt [b][d][s]  (f16, raw 16-bit moves)
__global__ void k_transpose_v(const u16* __restrict__ V, u16* __restrict__ Vt) {
    __shared__ u16 tile[32][33];
    const int b = blockIdx.z;
    const int s0 = blockIdx.x * 32, d0 = blockIdx.y * 32;
    const int c = threadIdx.x & 31, r0 = threadIdx.x >> 5;
    const u16* Vb = V + (size_t)b * SEQ * 1024;
    u16* Vtb = Vt + (size_t)b * 1024 * SEQ;
    #pragma unroll
    for (int rr = r0; rr < 32; rr += 8)
        tile[rr][c] = Vb[(size_t)(s0 + rr) * 1024 + d0 + c];
    __syncthreads();
    #pragma unroll
    for (int rr = r0; rr < 32; rr += 8)
        Vtb[(size_t)(d0 + rr) * SEQ + s0 + c] = tile[c][rr];
}

// scores[b] = Q[b] @ K[b]^T  (fp32 out, unscaled)
__global__ __launch_bounds__(256) void k_gemm_scores(
    const f16* __restrict__ Q, const f16* __restrict__ K, float* __restrict__ S)
{
    __shared__ __align__(16) char smem[32768];
    f32x4 acc[4][4];
    const int b = blockIdx.z;
    const f16* Qb = Q + (size_t)b * SEQ * 1024;
    const f16* Kb = K + (size_t)b * SEQ * 1024;
    gemm_tile((const char*)(Qb + (size_t)blockIdx.y * 128 * 1024),
              (const char*)(Kb + (size_t)blockIdx.x * 128 * 1024),
              1024, 1024, 1024 / 64, smem, acc);

    float* Sb = S + (size_t)b * SEQ * SEQ;
    const int lane = threadIdx.x & 63;
    const int wave = threadIdx.x >> 6;
    const int row0 = blockIdx.y * 128 + (wave >> 1) * 64;
    const int col0 = blockIdx.x * 128 + (wave & 1) * 64;
    #pragma unroll
    for (int m = 0; m < 4; ++m)
        #pragma unroll
        for (int n = 0; n < 4; ++n) {
            int col = col0 + n * 16 + (lane & 15);
            #pragma unroll
            for (int j = 0; j < 4; ++j) {
                int row = row0 + m * 16 + (lane >> 4) * 4 + j;
                Sb[(size_t)row * SEQ + col] = acc[m][n][j];
            }
        }
}

// row softmax: one block per row, 2048 fp32 in -> 2048 f16 out
__global__ __launch_bounds__(256) void k_softmax(
    const float* __restrict__ S, f16* __restrict__ P)
{
    const size_t row = blockIdx.x;
    const float* s = S + row * SEQ;
    f16* p = P + row * SEQ;
    const int t = threadIdx.x;

    f32x4 x0 = ((const f32x4*)s)[t * 2];
    f32x4 x1 = ((const f32x4*)s)[t * 2 + 1];
    float v[8] = {x0[0], x0[1], x0[2], x0[3], x1[0], x1[1], x1[2], x1[3]};

    float mx = v[0];
    #pragma unroll
    for (int j = 1; j < 8; ++j) mx = fmaxf(mx, v[j]);
    #pragma unroll
    for (int o = 32; o; o >>= 1) mx = fmaxf(mx, __shfl_xor(mx, o, 64));
    __shared__ float red[8];
    if ((t & 63) == 0) red[t >> 6] = mx;
    __syncthreads();
    mx = fmaxf(fmaxf(red[0], red[1]), fmaxf(red[2], red[3]));

    float sum = 0.f;
    #pragma unroll
    for (int j = 0; j < 8; ++j) { v[j] = __expf(v[j] - mx); sum += v[j]; }
    #pragma unroll
    for (int o = 32; o; o >>= 1) sum += __shfl_xor(sum, o, 64);
    if ((t & 63) == 0) red[4 + (t >> 6)] = sum;
    __syncthreads();
    sum = (red[4] + red[5]) + (red[6] + red[7]);
    float inv = 1.0f / sum;

    f16x8 o8;
    #pragma unroll
    for (int j = 0; j < 8; ++j) o8[j] = (f16)(v[j] * inv);
    ((f16x8*)p)[t] = o8;
}

// out[b] = (P[b] @ Vt[b]^T) / 32   (fp32 out)
__global__ __launch_bounds__(256) void k_gemm_pv(
    const f16* __restrict__ P, const f16* __restrict__ Vt, float* __restrict__ out)
{
    __shared__ __align__(16) char smem[32768];
    f32x4 acc[4][4];
    const int b = blockIdx.z;
    const f16* Pb  = P  + (size_t)b * SEQ * SEQ;
    const f16* Vtb = Vt + (size_t)b * 1024 * SEQ;
    gemm_tile((const char*)(Pb  + (size_t)blockIdx.y * 128 * SEQ),
              (const char*)(Vtb + (size_t)blockIdx.x * 128 * SEQ),
              SEQ, SEQ, SEQ / 64, smem, acc);

    float* ob = out + (size_t)b * SEQ * 1024;
    const int lane = threadIdx.x & 63;
    const int wave = threadIdx.x >> 6;
    const int row0 = blockIdx.y * 128 + (wave >> 1) * 64;
    const int col0 = blockIdx.x * 128 + (wave & 1) * 64;
    #pragma unroll
    for (int m = 0; m < 4; ++m)
        #pragma unroll
        for (int n = 0; n < 4; ++n) {
            int col = col0 + n * 16 + (lane & 15);
            #pragma unroll
            for (int j = 0; j < 4; ++j) {
                int row = row0 + m * 16 + (lane >> 4) * 4 + j;
                ob[(size_t)row * 1024 + col] = acc[m][n][j] * 0.03125f;
            }
        }
}

// ---------- launch ----------

extern "C" void kernel_launch(void* const* d_in, const int* in_sizes, int n_in,
                              void* d_out, int out_size, void* d_ws, size_t ws_size,
                              hipStream_t stream) {
    const float* x  = (const float*)d_in[0];
    const float* Wq = (const float*)d_in[1];
    const float* bq = (const float*)d_in[2];
    const float* Wk = (const float*)d_in[3];
    const float* bk = (const float*)d_in[4];
    const float* Wv = (const float*)d_in[5];
    const float* bv = (const float*)d_in[6];
    float* out = (float*)d_out;
    char* ws = (char*)d_ws;

    // workspace layout (MB offsets):
    //  [0,16)   Q        (P overlays after scores are consumed)
    //  [16,32)  K
    //  [32,48)  V        (dead after transpose)
    //  [48,64)  Vt
    //  [64,80)  xh       (dead after QKV gemm; S overlays)
    //  [80,86)  wt       (dead after QKV gemm; S overlays)
    //  [64,128) S        fp32 scores, 4 x 16MB, overlays xh+wt
    f16*  Q  = (f16*)(ws);
    f16*  K  = (f16*)(ws + (size_t)16 * MB);
    f16*  V  = (f16*)(ws + (size_t)32 * MB);
    f16*  Vt = (f16*)(ws + (size_t)48 * MB);
    f16*  xh = (f16*)(ws + (size_t)64 * MB);
    f16*  wt = (f16*)(ws + (size_t)80 * MB);
    float* S = (float*)(ws + (size_t)64 * MB);
    f16*  P  = Q;  // overlays dead Q

    const size_t needed = (size_t)128 * MB;
    if (ws_size < needed) return;

    k_convx<<<2048, 256, 0, stream>>>(x, xh, (NB * SEQ * DIN) / 8);
    k_wt<<<dim3(32, 32, 3), 256, 0, stream>>>(Wq, Wk, Wv, wt);
    k_gemm_qkv<<<dim3(24, 64), 256, 0, stream>>>(xh, wt, bq, bk, bv, Q, K, V);
    k_transpose_v<<<dim3(SEQ / 32, 1024 / 32, NB), 256, 0, stream>>>((const u16*)V, (u16*)Vt);
    k_gemm_scores<<<dim3(SEQ / 128, SEQ / 128, NB), 256, 0, stream>>>(Q, K, S);
    k_softmax<<<NB * SEQ, 256, 0, stream>>>(S, P);
    k_gemm_pv<<<dim3(1024 / 128, SEQ / 128, NB), 256, 0, stream>>>(P, Vt, out);
}

// Round 4
// 173.543 us; speedup vs baseline: 1.8015x; 1.1051x over previous
//
#include <hip/hip_runtime.h>
#include <stdint.h>

typedef unsigned short u16;
typedef _Float16 f16;
typedef _Float16 f16x8 __attribute__((ext_vector_type(8)));
typedef float f32x4 __attribute__((ext_vector_type(4)));

#define DIN 1024
#define SEQ 2048
#define NB 4
#define MB (1u << 20)

// ---------- helpers ----------

__device__ __forceinline__ void gload_lds16(const void* g, void* l) {
    __builtin_amdgcn_global_load_lds(
        (__attribute__((address_space(1))) void*)(uintptr_t)g,
        (__attribute__((address_space(3))) void*)l,
        16, 0, 0);
}

// XCD-aware bijective swizzle: hardware round-robins consecutive block ids
// across the 8 XCDs; remap so consecutive SEMANTIC tiles (which share an
// A-panel) land on the same XCD's L2. Requires nwg % 8 == 0 (all our grids).
__device__ __forceinline__ int xcd_swz(int h, int cpx) {
    return (h & 7) * cpx + (h >> 3);
}

// ---------- GEMM mainloop (f16) ----------
// C[128x128] += A[128xK] * B[128xK]^T  (both K-major f16). 4 waves 2x2,
// each wave a 64x64 tile of 4x4 16x16 frags. BK=64, XOR-swizzled LDS
// (byte ^= (row&7)<<4) via pre-swizzled global source (linear LDS dest).

__device__ __forceinline__ void gemm_tile(
    const char* __restrict__ A, const char* __restrict__ B,
    int lda, int ldb, int ksteps, char* smem, f32x4 acc[4][4])
{
    const int lane = threadIdx.x & 63;
    const int wave = threadIdx.x >> 6;

    #pragma unroll
    for (int m = 0; m < 4; ++m)
        #pragma unroll
        for (int n = 0; n < 4; ++n)
            acc[m][n] = (f32x4){0.f, 0.f, 0.f, 0.f};

    const char* ga[4];
    const char* gb[4];
    int ldsoff[4];
    #pragma unroll
    for (int i = 0; i < 4; ++i) {
        int La = (wave * 4 + i) * 1024 + lane * 16;
        int r  = La >> 7;
        int cb = La & 127;
        int sc = cb ^ ((r & 7) << 4);
        ga[i] = A + (size_t)r * (size_t)(lda * 2) + sc;
        gb[i] = B + (size_t)r * (size_t)(ldb * 2) + sc;
        ldsoff[i] = (wave * 4 + i) * 1024;
    }

    const int wr = (wave >> 1) * 64;
    const int wc = (wave & 1) * 64;

    for (int ks = 0; ks < ksteps; ++ks) {
        #pragma unroll
        for (int i = 0; i < 4; ++i) {
            gload_lds16(ga[i], smem + ldsoff[i]);
            gload_lds16(gb[i], smem + 16384 + ldsoff[i]);
            ga[i] += 128;
            gb[i] += 128;
        }
        __syncthreads();

        #pragma unroll
        for (int kk = 0; kk < 2; ++kk) {
            const int kb = kk * 64 + ((lane >> 4) << 4);
            f16x8 af[4], bfv[4];
            #pragma unroll
            for (int m = 0; m < 4; ++m) {
                int r = wr + m * 16 + (lane & 15);
                af[m] = *(const f16x8*)(smem + r * 128 + (kb ^ ((r & 7) << 4)));
            }
            #pragma unroll
            for (int n = 0; n < 4; ++n) {
                int r = wc + n * 16 + (lane & 15);
                bfv[n] = *(const f16x8*)(smem + 16384 + r * 128 + (kb ^ ((r & 7) << 4)));
            }
            #pragma unroll
            for (int m = 0; m < 4; ++m)
                #pragma unroll
                for (int n = 0; n < 4; ++n)
                    acc[m][n] = __builtin_amdgcn_mfma_f32_16x16x32_f16(
                        af[m], bfv[n], acc[m][n], 0, 0, 0);
        }
        __syncthreads();
    }
}

// ---------- kernels ----------

// Merged prep: blocks [0,2048) convert x fp32->f16; blocks [2048,5120)
// transpose+convert the three W matrices into wt [3*1024(n)][1024(k)] f16.
__global__ __launch_bounds__(256) void k_prep(
    const float* __restrict__ x, f16* __restrict__ xh,
    const float* __restrict__ Wq, const float* __restrict__ Wk,
    const float* __restrict__ Wv, f16* __restrict__ wt)
{
    __shared__ float tile[32][33];
    const int bid = blockIdx.x;
    if (bid < 2048) {
        const int n8 = (NB * SEQ * DIN) / 8;
        for (int idx = bid * 256 + threadIdx.x; idx < n8; idx += 2048 * 256) {
            f32x4 a = ((const f32x4*)x)[(size_t)idx * 2];
            f32x4 b = ((const f32x4*)x)[(size_t)idx * 2 + 1];
            f16x8 o;
            o[0] = (f16)a[0]; o[1] = (f16)a[1]; o[2] = (f16)a[2]; o[3] = (f16)a[3];
            o[4] = (f16)b[0]; o[5] = (f16)b[1]; o[6] = (f16)b[2]; o[7] = (f16)b[3];
            ((f16x8*)xh)[idx] = o;
        }
    } else {
        const int wb = bid - 2048;          // 0..3071
        const int mtx = wb >> 10;           // 0..2
        const int rem = wb & 1023;
        const int n0 = (rem & 31) * 32, k0 = (rem >> 5) * 32;
        const float* W = (mtx == 0) ? Wq : (mtx == 1 ? Wk : Wv);
        const int c = threadIdx.x & 31, r0 = threadIdx.x >> 5;
        #pragma unroll
        for (int rr = r0; rr < 32; rr += 8)
            tile[rr][c] = W[(size_t)(k0 + rr) * DIN + n0 + c];
        __syncthreads();
        f16* o = wt + (size_t)mtx * DIN * DIN;
        #pragma unroll
        for (int rr = r0; rr < 32; rr += 8)
            o[(size_t)(n0 + rr) * DIN + k0 + c] = (f16)tile[c][rr];
    }
}

// QKV = x @ W^T + bias. Q,K written row-major; V written TRANSPOSED into
// Vt[b][d][s] directly from the epilogue (saves the transpose kernel).
__global__ __launch_bounds__(256) void k_gemm_qkv(
    const f16* __restrict__ xh, const f16* __restrict__ wt,
    const float* __restrict__ bq, const float* __restrict__ bk,
    const float* __restrict__ bv,
    f16* __restrict__ Q, f16* __restrict__ K, f16* __restrict__ Vt)
{
    __shared__ __align__(16) char smem[32768];
    f32x4 acc[4][4];
    const int sid = xcd_swz(blockIdx.x, 192);   // 1536 blocks / 8
    const int blkN = sid % 24;
    const int blkM = sid / 24;
    gemm_tile((const char*)(xh + (size_t)blkM * 128 * DIN),
              (const char*)(wt + (size_t)blkN * 128 * DIN),
              DIN, DIN, DIN / 64, smem, acc);

    const int lane = threadIdx.x & 63;
    const int wave = threadIdx.x >> 6;
    const int row0 = blkM * 128 + (wave >> 1) * 64;
    const int col0 = blkN * 128 + (wave & 1) * 64;   // wave-uniform, 64-aligned

    if (col0 >= 2048) {
        // V columns: write transposed. Vt[b][d][s], b = row0>>11.
        const int bb = row0 >> 11;
        const int sb = row0 & (SEQ - 1);
        f16* Vtb = Vt + (size_t)bb * DIN * SEQ;
        #pragma unroll
        for (int n = 0; n < 4; ++n) {
            int d = (col0 - 2048) + n * 16 + (lane & 15);
            float bias = bv[d];
            #pragma unroll
            for (int m = 0; m < 4; ++m) {
                #pragma unroll
                for (int j = 0; j < 4; ++j) {
                    int s = sb + m * 16 + (lane >> 4) * 4 + j;
                    Vtb[(size_t)d * SEQ + s] = (f16)(acc[m][n][j] + bias);
                }
            }
        }
    } else {
        f16* dst = (col0 < 1024) ? Q : K;
        const float* bsrc = (col0 < 1024) ? bq : bk;
        const int ncb = col0 & 1023;
        #pragma unroll
        for (int n = 0; n < 4; ++n) {
            int nc = ncb + n * 16 + (lane & 15);
            float bias = bsrc[nc];
            #pragma unroll
            for (int m = 0; m < 4; ++m) {
                #pragma unroll
                for (int j = 0; j < 4; ++j) {
                    int row = row0 + m * 16 + (lane >> 4) * 4 + j;
                    dst[(size_t)row * 1024 + nc] = (f16)(acc[m][n][j] + bias);
                }
            }
        }
    }
}

// scores[b] = Q[b] @ K[b]^T  (fp32 out, unscaled)
__global__ __launch_bounds__(256) void k_gemm_scores(
    const f16* __restrict__ Q, const f16* __restrict__ K, float* __restrict__ S)
{
    __shared__ __align__(16) char smem[32768];
    f32x4 acc[4][4];
    const int sid = xcd_swz(blockIdx.x, 128);   // 1024 blocks / 8
    const int bx = sid & 15;            // K-block (cols)
    const int by = (sid >> 4) & 15;     // Q-block (rows)
    const int b  = sid >> 8;
    const f16* Qb = Q + (size_t)b * SEQ * 1024;
    const f16* Kb = K + (size_t)b * SEQ * 1024;
    gemm_tile((const char*)(Qb + (size_t)by * 128 * 1024),
              (const char*)(Kb + (size_t)bx * 128 * 1024),
              1024, 1024, 1024 / 64, smem, acc);

    float* Sb = S + (size_t)b * SEQ * SEQ;
    const int lane = threadIdx.x & 63;
    const int wave = threadIdx.x >> 6;
    const int row0 = by * 128 + (wave >> 1) * 64;
    const int col0 = bx * 128 + (wave & 1) * 64;
    #pragma unroll
    for (int m = 0; m < 4; ++m)
        #pragma unroll
        for (int n = 0; n < 4; ++n) {
            int col = col0 + n * 16 + (lane & 15);
            #pragma unroll
            for (int j = 0; j < 4; ++j) {
                int row = row0 + m * 16 + (lane >> 4) * 4 + j;
                Sb[(size_t)row * SEQ + col] = acc[m][n][j];
            }
        }
}

// row softmax: one block per row, 2048 fp32 in -> 2048 f16 out
__global__ __launch_bounds__(256) void k_softmax(
    const float* __restrict__ S, f16* __restrict__ P)
{
    const size_t row = blockIdx.x;
    const float* s = S + row * SEQ;
    f16* p = P + row * SEQ;
    const int t = threadIdx.x;

    f32x4 x0 = ((const f32x4*)s)[t * 2];
    f32x4 x1 = ((const f32x4*)s)[t * 2 + 1];
    float v[8] = {x0[0], x0[1], x0[2], x0[3], x1[0], x1[1], x1[2], x1[3]};

    float mx = v[0];
    #pragma unroll
    for (int j = 1; j < 8; ++j) mx = fmaxf(mx, v[j]);
    #pragma unroll
    for (int o = 32; o; o >>= 1) mx = fmaxf(mx, __shfl_xor(mx, o, 64));
    __shared__ float red[8];
    if ((t & 63) == 0) red[t >> 6] = mx;
    __syncthreads();
    mx = fmaxf(fmaxf(red[0], red[1]), fmaxf(red[2], red[3]));

    float sum = 0.f;
    #pragma unroll
    for (int j = 0; j < 8; ++j) { v[j] = __expf(v[j] - mx); sum += v[j]; }
    #pragma unroll
    for (int o = 32; o; o >>= 1) sum += __shfl_xor(sum, o, 64);
    if ((t & 63) == 0) red[4 + (t >> 6)] = sum;
    __syncthreads();
    sum = (red[4] + red[5]) + (red[6] + red[7]);
    float inv = 1.0f / sum;

    f16x8 o8;
    #pragma unroll
    for (int j = 0; j < 8; ++j) o8[j] = (f16)(v[j] * inv);
    ((f16x8*)p)[t] = o8;
}

// out[b] = (P[b] @ Vt[b]^T) / 32   (fp32 out)
__global__ __launch_bounds__(256) void k_gemm_pv(
    const f16* __restrict__ P, const f16* __restrict__ Vt, float* __restrict__ out)
{
    __shared__ __align__(16) char smem[32768];
    f32x4 acc[4][4];
    const int sid = xcd_swz(blockIdx.x, 64);   // 512 blocks / 8
    const int bx = sid & 7;             // d-block (cols)
    const int by = (sid >> 3) & 15;     // q-block (rows)
    const int b  = sid >> 7;
    const f16* Pb  = P  + (size_t)b * SEQ * SEQ;
    const f16* Vtb = Vt + (size_t)b * 1024 * SEQ;
    gemm_tile((const char*)(Pb  + (size_t)by * 128 * SEQ),
              (const char*)(Vtb + (size_t)bx * 128 * SEQ),
              SEQ, SEQ, SEQ / 64, smem, acc);

    float* ob = out + (size_t)b * SEQ * 1024;
    const int lane = threadIdx.x & 63;
    const int wave = threadIdx.x >> 6;
    const int row0 = by * 128 + (wave >> 1) * 64;
    const int col0 = bx * 128 + (wave & 1) * 64;
    #pragma unroll
    for (int m = 0; m < 4; ++m)
        #pragma unroll
        for (int n = 0; n < 4; ++n) {
            int col = col0 + n * 16 + (lane & 15);
            #pragma unroll
            for (int j = 0; j < 4; ++j) {
                int row = row0 + m * 16 + (lane >> 4) * 4 + j;
                ob[(size_t)row * 1024 + col] = acc[m][n][j] * 0.03125f;
            }
        }
}

// ---------- launch ----------

extern "C" void kernel_launch(void* const* d_in, const int* in_sizes, int n_in,
                              void* d_out, int out_size, void* d_ws, size_t ws_size,
                              hipStream_t stream) {
    const float* x  = (const float*)d_in[0];
    const float* Wq = (const float*)d_in[1];
    const float* bq = (const float*)d_in[2];
    const float* Wk = (const float*)d_in[3];
    const float* bk = (const float*)d_in[4];
    const float* Wv = (const float*)d_in[5];
    const float* bv = (const float*)d_in[6];
    float* out = (float*)d_out;
    char* ws = (char*)d_ws;

    // workspace layout (MB offsets):
    //  [0,16)   Q        (P overlays after scores are consumed)
    //  [16,32)  K
    //  [32,48)  Vt       (written directly by QKV epilogue)
    //  [48,64)  xh       (dead after QKV gemm)
    //  [64,70)  wt       (dead after QKV gemm)
    //  [48,112) S        fp32 scores, overlays xh+wt
    f16*  Q  = (f16*)(ws);
    f16*  K  = (f16*)(ws + (size_t)16 * MB);
    f16*  Vt = (f16*)(ws + (size_t)32 * MB);
    f16*  xh = (f16*)(ws + (size_t)48 * MB);
    f16*  wt = (f16*)(ws + (size_t)64 * MB);
    float* S = (float*)(ws + (size_t)48 * MB);
    f16*  P  = Q;  // overlays dead Q

    const size_t needed = (size_t)112 * MB;
    if (ws_size < needed) return;

    k_prep<<<5120, 256, 0, stream>>>(x, xh, Wq, Wk, Wv, wt);
    k_gemm_qkv<<<1536, 256, 0, stream>>>(xh, wt, bq, bk, bv, Q, K, Vt);
    k_gemm_scores<<<1024, 256, 0, stream>>>(Q, K, S);
    k_softmax<<<NB * SEQ, 256, 0, stream>>>(S, P);
    k_gemm_pv<<<512, 256, 0, stream>>>(P, Vt, out);
}